// Round 2
// baseline (666.969 us; speedup 1.0000x reference)
//
#include <hip/hip_runtime.h>
#include <hip/hip_bf16.h>

#define H 1024
#define V 50257
#define L 4096

__device__ __forceinline__ float sigmoidf_(float x) { return 1.f / (1.f + expf(-x)); }

__device__ __forceinline__ float dot4(float4 w, float4 c) {
    return w.x * c.x + w.y * c.y + w.z * c.z + w.w * c.w;
}

// ---------------- K1: GRU cell. grid=H blocks of 64 (one wave per output j) --
__global__ __launch_bounds__(64) void k_gru(const int* __restrict__ idx,
        const float* __restrict__ hidden, const float* __restrict__ emb,
        const float* __restrict__ w_ih, const float* __restrict__ w_hh,
        const float* __restrict__ b_ih, const float* __restrict__ b_hh,
        float* __restrict__ concat, float* __restrict__ out_h) {
    const int j = blockIdx.x;
    const int lane = threadIdx.x;
    const float* x   = emb + (size_t)idx[0] * H;
    const float* wir = w_ih + (size_t)j * H;
    const float* wiz = wir + (size_t)H * H;
    const float* win = wiz + (size_t)H * H;
    const float* whr = w_hh + (size_t)j * H;
    const float* whz = whr + (size_t)H * H;
    const float* whn = whz + (size_t)H * H;
    float sir = 0, siz = 0, sin_ = 0, shr = 0, shz = 0, shn = 0;
    #pragma unroll
    for (int it = 0; it < 4; ++it) {
        int elem = (it * 64 + lane) * 4;
        float4 xf = *(const float4*)(x + elem);
        float4 hf = *(const float4*)(hidden + elem);
        sir  += dot4(*(const float4*)(wir + elem), xf);
        siz  += dot4(*(const float4*)(wiz + elem), xf);
        sin_ += dot4(*(const float4*)(win + elem), xf);
        shr  += dot4(*(const float4*)(whr + elem), hf);
        shz  += dot4(*(const float4*)(whz + elem), hf);
        shn  += dot4(*(const float4*)(whn + elem), hf);
    }
    #pragma unroll
    for (int off = 32; off; off >>= 1) {
        sir += __shfl_xor(sir, off); siz += __shfl_xor(siz, off);
        sin_ += __shfl_xor(sin_, off); shr += __shfl_xor(shr, off);
        shz += __shfl_xor(shz, off); shn += __shfl_xor(shn, off);
    }
    if (lane == 0) {
        float r = sigmoidf_(sir + b_ih[j]       + shr + b_hh[j]);
        float z = sigmoidf_(siz + b_ih[H + j]   + shz + b_hh[H + j]);
        float n = tanhf(sin_ + b_ih[2*H + j] + r * (shn + b_hh[2*H + j]));
        float hn = (1.f - z) * n + z * hidden[j];
        concat[H + j] = hn;
        out_h[j] = hn;
    }
}

// ---------------- K2: scores[l] = enc[l] . h_new. one wave per row -----------
__global__ __launch_bounds__(256) void k_scores(const float* __restrict__ enc,
        const float* __restrict__ concat, float* __restrict__ scores) {
    const int wave = threadIdx.x >> 6, lane = threadIdx.x & 63;
    const int l = blockIdx.x * 4 + wave;
    const float* row = enc + (size_t)l * H;
    const float* h = concat + H;
    float s = 0.f;
    #pragma unroll
    for (int it = 0; it < 4; ++it) {
        int elem = (it * 64 + lane) * 4;
        s += dot4(*(const float4*)(row + elem), *(const float4*)(h + elem));
    }
    #pragma unroll
    for (int off = 32; off; off >>= 1) s += __shfl_xor(s, off);
    if (lane == 0) scores[l] = s;
}

// ---------------- K3: softmax over 4096 scores. single block 256 -------------
__global__ __launch_bounds__(256) void k_softmax(const float* __restrict__ scores,
                                                 float* __restrict__ attn) {
    __shared__ float sm[8];
    const int t = threadIdx.x, lane = t & 63, wave = t >> 6;
    float v[16];
    float m = -INFINITY;
    #pragma unroll
    for (int i = 0; i < 16; ++i) { v[i] = scores[i * 256 + t]; m = fmaxf(m, v[i]); }
    #pragma unroll
    for (int off = 32; off; off >>= 1) m = fmaxf(m, __shfl_xor(m, off));
    if (lane == 0) sm[wave] = m;
    __syncthreads();
    m = fmaxf(fmaxf(sm[0], sm[1]), fmaxf(sm[2], sm[3]));
    float s = 0.f;
    #pragma unroll
    for (int i = 0; i < 16; ++i) { v[i] = expf(v[i] - m); s += v[i]; }
    #pragma unroll
    for (int off = 32; off; off >>= 1) s += __shfl_xor(s, off);
    __syncthreads();
    if (lane == 0) sm[wave] = s;
    __syncthreads();
    s = sm[0] + sm[1] + sm[2] + sm[3];
    float inv = 1.f / s;
    #pragma unroll
    for (int i = 0; i < 16; ++i) attn[i * 256 + t] = v[i] * inv;
}

// ---------------- K4: ctx partials. 16 row-chunks x full width ---------------
__global__ __launch_bounds__(256) void k_ctx_partial(const float* __restrict__ enc,
        const float* __restrict__ attn, float* __restrict__ partial) {
    __shared__ float a[256];
    const int t = threadIdx.x;
    const int r0 = blockIdx.x * 256;
    a[t] = attn[r0 + t];
    __syncthreads();
    float acc0 = 0, acc1 = 0, acc2 = 0, acc3 = 0;
    const float* p = enc + (size_t)r0 * H + t * 4;
    for (int l = 0; l < 256; ++l) {
        float4 w = *(const float4*)p; p += H;
        float al = a[l];
        acc0 += al * w.x; acc1 += al * w.y; acc2 += al * w.z; acc3 += al * w.w;
    }
    *(float4*)(partial + (size_t)blockIdx.x * H + t * 4) = make_float4(acc0, acc1, acc2, acc3);
}

// ---------------- K4b: reduce 16 partials -> ctx = concat[0..1023] -----------
__global__ __launch_bounds__(256) void k_ctx_reduce(const float* __restrict__ partial,
                                                    float* __restrict__ concat) {
    const int c = blockIdx.x * 256 + threadIdx.x;
    float s = 0.f;
    #pragma unroll
    for (int p = 0; p < 16; ++p) s += partial[p * H + c];
    concat[c] = s;
}

// ---------------- K5: logits[v] = out_w[v] . concat + out_b[v] ---------------
__global__ __launch_bounds__(256) void k_logits(const float* __restrict__ out_w,
        const float* __restrict__ out_b, const float* __restrict__ concat,
        float* __restrict__ logits) {
    const int wave = threadIdx.x >> 6, lane = threadIdx.x & 63;
    const int v = blockIdx.x * 4 + wave;
    if (v >= V) return;
    const float* row = out_w + (size_t)v * (2 * H);
    float s = 0.f;
    #pragma unroll
    for (int it = 0; it < 8; ++it) {
        int elem = (it * 64 + lane) * 4;
        s += dot4(*(const float4*)(row + elem), *(const float4*)(concat + elem));
    }
    #pragma unroll
    for (int off = 32; off; off >>= 1) s += __shfl_xor(s, off);
    if (lane == 0) logits[v] = s + out_b[v];
}

// ---------------- K6a: per-block online (max, sumexp) partials ---------------
__global__ __launch_bounds__(256) void k_lse_partial(const float* __restrict__ logits,
                                                     float* __restrict__ red) {
    __shared__ float sm[4], ss[4];
    const int t = threadIdx.x;
    const int i = blockIdx.x * 256 + t;
    float m = -INFINITY, s = 0.f;
    for (int v = i; v < V; v += 64 * 256) {
        float x = logits[v];
        float M = fmaxf(m, x);
        s = s * expf(m - M) + expf(x - M);
        m = M;
    }
    const int lane = t & 63, wave = t >> 6;
    #pragma unroll
    for (int off = 32; off; off >>= 1) {
        float m2 = __shfl_xor(m, off), s2 = __shfl_xor(s, off);
        float M = fmaxf(m, m2);
        s = s * expf(m - M) + s2 * expf(m2 - M);
        m = M;
    }
    if (lane == 0) { sm[wave] = m; ss[wave] = s; }
    __syncthreads();
    if (t == 0) {
        float M = fmaxf(fmaxf(sm[0], sm[1]), fmaxf(sm[2], sm[3]));
        float S = ss[0] * expf(sm[0] - M) + ss[1] * expf(sm[1] - M) +
                  ss[2] * expf(sm[2] - M) + ss[3] * expf(sm[3] - M);
        red[blockIdx.x] = M;
        red[64 + blockIdx.x] = S;
    }
}

// ---------------- K6b: final logsumexp constant ------------------------------
__global__ __launch_bounds__(64) void k_lse_final(const float* __restrict__ red,
                                                  float* __restrict__ C) {
    const int lane = threadIdx.x;
    float m = red[lane], s = red[64 + lane];
    #pragma unroll
    for (int off = 32; off; off >>= 1) {
        float m2 = __shfl_xor(m, off), s2 = __shfl_xor(s, off);
        float M = fmaxf(m, m2);
        s = s * expf(m - M) + s2 * expf(m2 - M);
        m = M;
    }
    if (lane == 0) C[0] = m + logf(s);
}

// ---------------- K7: write log_softmax to output ----------------------------
__global__ __launch_bounds__(256) void k_write(const float* __restrict__ logits,
        const float* __restrict__ C, float* __restrict__ out) {
    const int v = blockIdx.x * 256 + threadIdx.x;
    if (v < V) out[v] = logits[v] - C[0];
}

extern "C" void kernel_launch(void* const* d_in, const int* in_sizes, int n_in,
                              void* d_out, int out_size, void* d_ws, size_t ws_size,
                              hipStream_t stream) {
    const int*   idx    = (const int*)d_in[0];
    const float* hidden = (const float*)d_in[1];
    const float* enc    = (const float*)d_in[2];
    const float* emb    = (const float*)d_in[3];
    const float* w_ih   = (const float*)d_in[4];
    const float* w_hh   = (const float*)d_in[5];
    const float* b_ih   = (const float*)d_in[6];
    const float* b_hh   = (const float*)d_in[7];
    const float* out_w  = (const float*)d_in[8];
    const float* out_b  = (const float*)d_in[9];
    float* out = (float*)d_out;   // [V] log_softmax | [H] h_new

    float* ws      = (float*)d_ws;
    float* concat  = ws;           // [2048] : ctx | h_new
    float* scores  = ws + 2048;    // [4096]
    float* attn    = ws + 6144;    // [4096]
    float* partial = ws + 10240;   // [16*1024]
    float* logits  = ws + 26624;   // [50257]
    float* red     = ws + 76896;   // [128] : m[64] | s[64]
    float* Cv      = ws + 77056;   // [1]

    k_gru<<<H, 64, 0, stream>>>(idx, hidden, emb, w_ih, w_hh, b_ih, b_hh, concat, out + V);
    k_scores<<<L / 4, 256, 0, stream>>>(enc, concat, scores);
    k_softmax<<<1, 256, 0, stream>>>(scores, attn);
    k_ctx_partial<<<16, 256, 0, stream>>>(enc, attn, partial);
    k_ctx_reduce<<<4, 256, 0, stream>>>(partial, concat);
    k_logits<<<(V + 3) / 4, 256, 0, stream>>>(out_w, out_b, concat, logits);
    k_lse_partial<<<64, 256, 0, stream>>>(logits, red);
    k_lse_final<<<1, 64, 0, stream>>>(red, Cv);
    k_write<<<(V + 255) / 256, 256, 0, stream>>>(logits, Cv, out);
}

// Round 3
// 657.945 us; speedup vs baseline: 1.0137x; 1.0137x over previous
//
#include <hip/hip_runtime.h>
#include <hip/hip_bf16.h>

#define H 1024
#define V 50257
#define L 4096
#define CTXB 128          // blocks for ctx partial
#define ROWS (L / CTXB)   // 32 rows per block

__device__ __forceinline__ float sigmoidf_(float x) { return 1.f / (1.f + expf(-x)); }

__device__ __forceinline__ float dot4(float4 w, float4 c) {
    return w.x * c.x + w.y * c.y + w.z * c.z + w.w * c.w;
}

// ---------------- K1: GRU cell. grid=H blocks of 64 (one wave per output j) --
__global__ __launch_bounds__(64) void k_gru(const int* __restrict__ idx,
        const float* __restrict__ hidden, const float* __restrict__ emb,
        const float* __restrict__ w_ih, const float* __restrict__ w_hh,
        const float* __restrict__ b_ih, const float* __restrict__ b_hh,
        float* __restrict__ concat, float* __restrict__ out_h) {
    const int j = blockIdx.x;
    const int lane = threadIdx.x;
    const float* x   = emb + (size_t)idx[0] * H;
    const float* wir = w_ih + (size_t)j * H;
    const float* wiz = wir + (size_t)H * H;
    const float* win = wiz + (size_t)H * H;
    const float* whr = w_hh + (size_t)j * H;
    const float* whz = whr + (size_t)H * H;
    const float* whn = whz + (size_t)H * H;
    float sir = 0, siz = 0, sin_ = 0, shr = 0, shz = 0, shn = 0;
    #pragma unroll
    for (int it = 0; it < 4; ++it) {
        int elem = (it * 64 + lane) * 4;
        float4 xf = *(const float4*)(x + elem);
        float4 hf = *(const float4*)(hidden + elem);
        sir  += dot4(*(const float4*)(wir + elem), xf);
        siz  += dot4(*(const float4*)(wiz + elem), xf);
        sin_ += dot4(*(const float4*)(win + elem), xf);
        shr  += dot4(*(const float4*)(whr + elem), hf);
        shz  += dot4(*(const float4*)(whz + elem), hf);
        shn  += dot4(*(const float4*)(whn + elem), hf);
    }
    #pragma unroll
    for (int off = 32; off; off >>= 1) {
        sir += __shfl_xor(sir, off); siz += __shfl_xor(siz, off);
        sin_ += __shfl_xor(sin_, off); shr += __shfl_xor(shr, off);
        shz += __shfl_xor(shz, off); shn += __shfl_xor(shn, off);
    }
    if (lane == 0) {
        float r = sigmoidf_(sir + b_ih[j]       + shr + b_hh[j]);
        float z = sigmoidf_(siz + b_ih[H + j]   + shz + b_hh[H + j]);
        float n = tanhf(sin_ + b_ih[2*H + j] + r * (shn + b_hh[2*H + j]));
        float hn = (1.f - z) * n + z * hidden[j];
        concat[H + j] = hn;
        out_h[j] = hn;
    }
}

// ---------------- K2: scores[l] = enc[l] . h_new. one wave per row -----------
__global__ __launch_bounds__(256) void k_scores(const float* __restrict__ enc,
        const float* __restrict__ concat, float* __restrict__ scores) {
    const int wave = threadIdx.x >> 6, lane = threadIdx.x & 63;
    const int l = blockIdx.x * 4 + wave;
    const float* row = enc + (size_t)l * H;
    const float* h = concat + H;
    float s = 0.f;
    #pragma unroll
    for (int it = 0; it < 4; ++it) {
        int elem = (it * 64 + lane) * 4;
        s += dot4(*(const float4*)(row + elem), *(const float4*)(h + elem));
    }
    #pragma unroll
    for (int off = 32; off; off >>= 1) s += __shfl_xor(s, off);
    if (lane == 0) scores[l] = s;
}

// ---------------- K3: softmax over 4096 scores. single block 256 -------------
__global__ __launch_bounds__(256) void k_softmax(const float* __restrict__ scores,
                                                 float* __restrict__ attn) {
    __shared__ float sm[8];
    const int t = threadIdx.x, lane = t & 63, wave = t >> 6;
    float v[16];
    float m = -INFINITY;
    #pragma unroll
    for (int i = 0; i < 16; ++i) { v[i] = scores[i * 256 + t]; m = fmaxf(m, v[i]); }
    #pragma unroll
    for (int off = 32; off; off >>= 1) m = fmaxf(m, __shfl_xor(m, off));
    if (lane == 0) sm[wave] = m;
    __syncthreads();
    m = fmaxf(fmaxf(sm[0], sm[1]), fmaxf(sm[2], sm[3]));
    float s = 0.f;
    #pragma unroll
    for (int i = 0; i < 16; ++i) { v[i] = expf(v[i] - m); s += v[i]; }
    #pragma unroll
    for (int off = 32; off; off >>= 1) s += __shfl_xor(s, off);
    __syncthreads();
    if (lane == 0) sm[wave] = s;
    __syncthreads();
    s = sm[0] + sm[1] + sm[2] + sm[3];
    float inv = 1.f / s;
    #pragma unroll
    for (int i = 0; i < 16; ++i) attn[i * 256 + t] = v[i] * inv;
}

// ---------------- K4: ctx partials. 128 blocks x 32 rows, unroll 8 -----------
__global__ __launch_bounds__(256) void k_ctx_partial(const float* __restrict__ enc,
        const float* __restrict__ attn, float* __restrict__ partial) {
    __shared__ float a[ROWS];
    const int t = threadIdx.x;
    const int r0 = blockIdx.x * ROWS;
    if (t < ROWS) a[t] = attn[r0 + t];
    __syncthreads();
    float acc0 = 0, acc1 = 0, acc2 = 0, acc3 = 0;
    const float* p = enc + (size_t)r0 * H + t * 4;
    #pragma unroll
    for (int l0 = 0; l0 < ROWS; l0 += 8) {
        float4 w[8];
        #pragma unroll
        for (int k = 0; k < 8; ++k) w[k] = *(const float4*)(p + (size_t)(l0 + k) * H);
        #pragma unroll
        for (int k = 0; k < 8; ++k) {
            float al = a[l0 + k];
            acc0 += al * w[k].x; acc1 += al * w[k].y;
            acc2 += al * w[k].z; acc3 += al * w[k].w;
        }
    }
    *(float4*)(partial + (size_t)blockIdx.x * H + t * 4) = make_float4(acc0, acc1, acc2, acc3);
}

// ---------------- K4b: reduce partials -> ctx = concat[0..1023] --------------
__global__ __launch_bounds__(256) void k_ctx_reduce(const float* __restrict__ partial,
                                                    float* __restrict__ concat) {
    const int c = blockIdx.x * 256 + threadIdx.x;
    float s = 0.f;
    for (int p = 0; p < CTXB; ++p) s += partial[(size_t)p * H + c];
    concat[c] = s;
}

// ---------------- K5: logits[v] = out_w[v] . concat + out_b[v] ---------------
__global__ __launch_bounds__(256) void k_logits(const float* __restrict__ out_w,
        const float* __restrict__ out_b, const float* __restrict__ concat,
        float* __restrict__ logits) {
    const int wave = threadIdx.x >> 6, lane = threadIdx.x & 63;
    const int v = blockIdx.x * 4 + wave;
    if (v >= V) return;
    const float* row = out_w + (size_t)v * (2 * H);
    float s = 0.f;
    #pragma unroll
    for (int it = 0; it < 8; ++it) {
        int elem = (it * 64 + lane) * 4;
        s += dot4(*(const float4*)(row + elem), *(const float4*)(concat + elem));
    }
    #pragma unroll
    for (int off = 32; off; off >>= 1) s += __shfl_xor(s, off);
    if (lane == 0) logits[v] = s + out_b[v];
}

// ---------------- K6: per-block online (max, sumexp) partials ----------------
__global__ __launch_bounds__(256) void k_lse_partial(const float* __restrict__ logits,
                                                     float* __restrict__ red) {
    __shared__ float sm[4], ss[4];
    const int t = threadIdx.x;
    const int i = blockIdx.x * 256 + t;
    float m = -INFINITY, s = 0.f;
    for (int v = i; v < V; v += 64 * 256) {
        float x = logits[v];
        float M = fmaxf(m, x);
        s = s * expf(m - M) + expf(x - M);
        m = M;
    }
    const int lane = t & 63, wave = t >> 6;
    #pragma unroll
    for (int off = 32; off; off >>= 1) {
        float m2 = __shfl_xor(m, off), s2 = __shfl_xor(s, off);
        float M = fmaxf(m, m2);
        s = s * expf(m - M) + s2 * expf(m2 - M);
        m = M;
    }
    if (lane == 0) { sm[wave] = m; ss[wave] = s; }
    __syncthreads();
    if (t == 0) {
        float M = fmaxf(fmaxf(sm[0], sm[1]), fmaxf(sm[2], sm[3]));
        float S = ss[0] * expf(sm[0] - M) + ss[1] * expf(sm[1] - M) +
                  ss[2] * expf(sm[2] - M) + ss[3] * expf(sm[3] - M);
        red[blockIdx.x] = M;
        red[64 + blockIdx.x] = S;
    }
}

// ---------------- K7: finalize C per-block + write log_softmax ---------------
__global__ __launch_bounds__(256) void k_write(const float* __restrict__ logits,
        const float* __restrict__ red, float* __restrict__ out) {
    __shared__ float sC;
    const int t = threadIdx.x;
    if (t < 64) {
        float m = red[t], s = red[64 + t];
        #pragma unroll
        for (int off = 32; off; off >>= 1) {
            float m2 = __shfl_xor(m, off), s2 = __shfl_xor(s, off);
            float M = fmaxf(m, m2);
            s = s * expf(m - M) + s2 * expf(m2 - M);
            m = M;
        }
        if (t == 0) sC = m + logf(s);
    }
    __syncthreads();
    const float C = sC;
    const int v = blockIdx.x * 256 + t;
    if (v < V) out[v] = logits[v] - C;
}

extern "C" void kernel_launch(void* const* d_in, const int* in_sizes, int n_in,
                              void* d_out, int out_size, void* d_ws, size_t ws_size,
                              hipStream_t stream) {
    const int*   idx    = (const int*)d_in[0];
    const float* hidden = (const float*)d_in[1];
    const float* enc    = (const float*)d_in[2];
    const float* emb    = (const float*)d_in[3];
    const float* w_ih   = (const float*)d_in[4];
    const float* w_hh   = (const float*)d_in[5];
    const float* b_ih   = (const float*)d_in[6];
    const float* b_hh   = (const float*)d_in[7];
    const float* out_w  = (const float*)d_in[8];
    const float* out_b  = (const float*)d_in[9];
    float* out = (float*)d_out;   // [V] log_softmax | [H] h_new

    float* ws      = (float*)d_ws;
    float* concat  = ws;            // [2048] : ctx | h_new
    float* scores  = ws + 2048;     // [4096]
    float* attn    = ws + 6144;     // [4096]
    float* partial = ws + 10240;    // [CTXB*1024]
    float* logits  = ws + 141312;   // [50257]
    float* red     = ws + 191584;   // [128] : m[64] | s[64]

    k_gru<<<H, 64, 0, stream>>>(idx, hidden, emb, w_ih, w_hh, b_ih, b_hh, concat, out + V);
    k_scores<<<L / 4, 256, 0, stream>>>(enc, concat, scores);
    k_softmax<<<1, 256, 0, stream>>>(scores, attn);
    k_ctx_partial<<<CTXB, 256, 0, stream>>>(enc, attn, partial);
    k_ctx_reduce<<<4, 256, 0, stream>>>(partial, concat);
    k_logits<<<(V + 3) / 4, 256, 0, stream>>>(out_w, out_b, concat, logits);
    k_lse_partial<<<64, 256, 0, stream>>>(logits, red);
    k_write<<<(V + 255) / 256, 256, 0, stream>>>(logits, red, out);
}